// Round 1
// baseline (17711.462 us; speedup 1.0000x reference)
//
#include <hip/hip_runtime.h>
#include <hip/hip_bf16.h>

// 5-layer LSTM, B=64, T=256, H=1024. bf16 MFMA (16x16x32), fp32 state.
// Round 1: per-timestep kernels (1280 launches), fused x+h matmul (K=2048).

using bf16x8 = __attribute__((ext_vector_type(8))) __bf16;
using f32x4  = __attribute__((ext_vector_type(4))) float;

#define Tn 256
#define Bn 64
#define Hn 1024

// ---------------------------------------------------------------------------
// Weight conversion: Wg[l][k][unit] (fp32, [5][2048][1024] each gate) ->
// Wperm[l][blk][r32][k] bf16, blk=0..127 (8 units each), r32 = g*8+uu,
// k = 0..2047 (u-dim: 0..1023 = x-part, 1024..2047 = h-part).
// B-fragment reads want 8 contiguous k for a fixed column -> k innermost.
__global__ void convW(const float* __restrict__ Wi, const float* __restrict__ Wf,
                      const float* __restrict__ Wc, const float* __restrict__ Wo,
                      __bf16* __restrict__ Wperm) {
    int gid = blockIdx.x * 256 + threadIdx.x;      // 5*128*32*256 = 5,242,880
    int k8  = gid & 255;                           // 256 chunks of 8 k
    int r32 = (gid >> 8) & 31;
    int blk = (gid >> 13) & 127;
    int l   = gid >> 20;
    int g   = r32 >> 3;
    int uu  = r32 & 7;
    int unit = blk * 8 + uu;
    const float* Wg = (g == 0) ? Wi : (g == 1) ? Wf : (g == 2) ? Wc : Wo;
    const float* src = Wg + ((size_t)l * 2048 + k8 * 8) * 1024 + unit;
    bf16x8 v;
#pragma unroll
    for (int j = 0; j < 8; ++j) v[j] = (__bf16)src[(size_t)j * 1024];
    *(bf16x8*)(Wperm + (size_t)gid * 8) = v;
}

// x[b][t][k] fp32 -> seq[t][b][k] bf16
__global__ void convX(const float* __restrict__ x, __bf16* __restrict__ seq) {
    int gid = blockIdx.x * 256 + threadIdx.x;      // 256*64*128 = 2,097,152
    int k8 = gid & 127;
    int b  = (gid >> 7) & 63;
    int t  = gid >> 13;
    const float* src = x + ((size_t)b * Tn + t) * Hn + k8 * 8;
    bf16x8 v;
#pragma unroll
    for (int j = 0; j < 8; ++j) v[j] = (__bf16)src[j];
    *(bf16x8*)(seq + (size_t)gid * 8) = v;
}

// ---------------------------------------------------------------------------
// One LSTM timestep. grid 128 blocks x 512 threads (8 waves).
// Block handles 8 hidden units (32 gate-columns). Waves K-split u (2048):
// wave w covers u-k in [256w, 256w+256); w<4 -> x-part, w>=4 -> h-part.
template <int FIRST>
__global__ __launch_bounds__(512) void lstm_step(
    const __bf16* __restrict__ xin,   // [T][B][H] input sequence (prev layer)
    __bf16* __restrict__ hout,        // [T][B][H] output sequence (this layer)
    const __bf16* __restrict__ Wl,    // [128][32][2048]
    const float* __restrict__ bi, const float* __restrict__ bfv,
    const float* __restrict__ bc, const float* __restrict__ bo,
    float* __restrict__ cst,          // [H][B] cell state fp32
    int t) {
    const int tid  = threadIdx.x;
    const int w    = tid >> 6;
    const int lane = tid & 63;
    const int l15  = lane & 15;
    const int lhi  = lane >> 4;       // 0..3

    __shared__ float zp[8][64][34];

    f32x4 acc[4][2] = {};

    if (!(FIRST && w >= 4)) {
        const int kb = w * 256;       // u-dim base
        const __bf16* asrc;
        int klocal;
        if (w < 4) { asrc = xin  + ((size_t)t * Bn) * Hn;       klocal = kb; }
        else       { asrc = hout + ((size_t)(t - 1) * Bn) * Hn; klocal = kb - 1024; }
        const __bf16* wblk = Wl + (size_t)blockIdx.x * 32 * 2048;

        const __bf16* arow[4];
#pragma unroll
        for (int i = 0; i < 4; ++i)
            arow[i] = asrc + (size_t)(16 * i + l15) * Hn + klocal + 8 * lhi;
        const __bf16* brow[2];
#pragma unroll
        for (int nf = 0; nf < 2; ++nf)
            brow[nf] = wblk + (size_t)(16 * nf + l15) * 2048 + kb + 8 * lhi;

#pragma unroll
        for (int kt = 0; kt < 8; ++kt) {
            bf16x8 a[4], bb[2];
#pragma unroll
            for (int i = 0; i < 4; ++i) a[i] = *(const bf16x8*)(arow[i] + kt * 32);
#pragma unroll
            for (int nf = 0; nf < 2; ++nf) bb[nf] = *(const bf16x8*)(brow[nf] + kt * 32);
#pragma unroll
            for (int i = 0; i < 4; ++i)
#pragma unroll
                for (int nf = 0; nf < 2; ++nf)
                    acc[i][nf] = __builtin_amdgcn_mfma_f32_16x16x32_bf16(
                        a[i], bb[nf], acc[i][nf], 0, 0, 0);
        }

        // C/D layout: col = lane&15, row = (lane>>4)*4 + j
#pragma unroll
        for (int i = 0; i < 4; ++i)
#pragma unroll
            for (int nf = 0; nf < 2; ++nf)
#pragma unroll
                for (int j = 0; j < 4; ++j)
                    zp[w][16 * i + 4 * lhi + j][16 * nf + l15] = acc[i][nf][j];
    }
    __syncthreads();

    // Elementwise: 512 threads, one (b, unit) pair each.
    const int b  = tid & 63;
    const int uu = tid >> 6;          // 0..7
    float z0 = 0.f, z1 = 0.f, z2 = 0.f, z3 = 0.f;
    const int NW = FIRST ? 4 : 8;
    for (int w2 = 0; w2 < NW; ++w2) {
        z0 += zp[w2][b][uu];
        z1 += zp[w2][b][8 + uu];
        z2 += zp[w2][b][16 + uu];
        z3 += zp[w2][b][24 + uu];
    }
    const int unit = blockIdx.x * 8 + uu;
    float zi = z0 + bi[unit];
    float zf = z1 + bfv[unit];
    float zg = z2 + bc[unit];
    float zo = z3 + bo[unit];
    float ii = 1.f / (1.f + expf(-zi));
    float ff = 1.f / (1.f + expf(-zf));
    float gg = tanhf(zg);
    float oo = 1.f / (1.f + expf(-zo));
    float cp = FIRST ? 0.f : cst[(size_t)unit * Bn + b];
    float cn = cp * ff + ii * gg;
    cst[(size_t)unit * Bn + b] = cn;
    hout[((size_t)t * Bn + b) * Hn + unit] = (__bf16)(oo * tanhf(cn));
}

// ---------------------------------------------------------------------------
// out[b] = dot(h5[T-1][b][:], Wfc) + bfc
__global__ void fc_kernel(const __bf16* __restrict__ seq, const float* __restrict__ Wfc,
                          const float* __restrict__ bfc, float* __restrict__ out) {
    int b = blockIdx.x;
    int tid = threadIdx.x;
    const __bf16* h = seq + ((size_t)(Tn - 1) * Bn + b) * Hn;
    float s = 0.f;
    for (int k = tid; k < Hn; k += 256) s += (float)h[k] * Wfc[k];
#pragma unroll
    for (int off = 32; off > 0; off >>= 1) s += __shfl_down(s, off);
    __shared__ float red[4];
    if ((tid & 63) == 0) red[tid >> 6] = s;
    __syncthreads();
    if (tid == 0) out[b] = red[0] + red[1] + red[2] + red[3] + bfc[0];
}

// ---------------------------------------------------------------------------
extern "C" void kernel_launch(void* const* d_in, const int* in_sizes, int n_in,
                              void* d_out, int out_size, void* d_ws, size_t ws_size,
                              hipStream_t stream) {
    const float* x   = (const float*)d_in[0];
    const float* Wi  = (const float*)d_in[1];
    const float* bi  = (const float*)d_in[2];
    const float* Wf  = (const float*)d_in[3];
    const float* bf  = (const float*)d_in[4];
    const float* Wc  = (const float*)d_in[5];
    const float* bc  = (const float*)d_in[6];
    const float* Wo  = (const float*)d_in[7];
    const float* bo  = (const float*)d_in[8];
    const float* Wfc = (const float*)d_in[9];
    const float* bfc = (const float*)d_in[10];

    char* ws = (char*)d_ws;
    __bf16* Wperm = (__bf16*)ws;                                   // 83,886,080 B
    __bf16* seqA  = (__bf16*)(ws + 83886080);                      // 33,554,432 B
    __bf16* seqB  = (__bf16*)(ws + 83886080 + 33554432);           // 33,554,432 B
    float*  cst   = (float*)(ws + 83886080 + 2 * 33554432);        //    262,144 B

    hipLaunchKernelGGL(convW, dim3(20480), dim3(256), 0, stream, Wi, Wf, Wc, Wo, Wperm);
    hipLaunchKernelGGL(convX, dim3(8192), dim3(256), 0, stream, x, seqA);

    const __bf16* in = seqA;
    __bf16* out = seqB;
    for (int l = 0; l < 5; ++l) {
        const __bf16* Wl = Wperm + (size_t)l * 128 * 32 * 2048;
        const float* bil = bi + l * 1024;
        const float* bfl = bf + l * 1024;
        const float* bcl = bc + l * 1024;
        const float* bol = bo + l * 1024;
        for (int t = 0; t < Tn; ++t) {
            if (t == 0)
                hipLaunchKernelGGL((lstm_step<1>), dim3(128), dim3(512), 0, stream,
                                   in, out, Wl, bil, bfl, bcl, bol, cst, t);
            else
                hipLaunchKernelGGL((lstm_step<0>), dim3(128), dim3(512), 0, stream,
                                   in, out, Wl, bil, bfl, bcl, bol, cst, t);
        }
        __bf16* tmp = out;
        out = (__bf16*)in;
        in = tmp;
    }
    hipLaunchKernelGGL(fc_kernel, dim3(64), dim3(256), 0, stream, in, Wfc, bfc, (float*)d_out);
}